// Round 6
// baseline (200.536 us; speedup 1.0000x reference)
//
#include <hip/hip_runtime.h>

typedef __bf16 bf16;
typedef __bf16 bf16x4v __attribute__((ext_vector_type(4)));
typedef __bf16 bf16x8 __attribute__((ext_vector_type(8)));
typedef float f32x4 __attribute__((ext_vector_type(4)));
typedef short s16x4 __attribute__((ext_vector_type(4)));

#define MFMA_X32(A, B, C) __builtin_amdgcn_mfma_f32_16x16x32_bf16(A, B, C, 0, 0, 0)

static __device__ __forceinline__ float fast_exp2(float x) {
  float r;
  asm volatile("v_exp_f32 %0, %1\n\ts_nop 0" : "=v"(r) : "v"(x));
  return r;
}

static __device__ __forceinline__ void gll16(const void* g, void* l) {
  __builtin_amdgcn_global_load_lds(
      (const __attribute__((address_space(1))) void*)g,
      (__attribute__((address_space(3))) void*)l, 16, 0, 0);
}

// Counted-vmcnt barrier (T4): prefetches stay in flight ACROSS the barrier.
// asm "memory" fences on both sides keep the compiler from moving ds_reads
// between my wait and the other waves' waits.
#define WAIT_BARRIER(N)                                        \
  {                                                            \
    asm volatile("s_waitcnt vmcnt(" #N ")" ::: "memory");      \
    __builtin_amdgcn_s_barrier();                              \
    asm volatile("" ::: "memory");                             \
  }

// ---- workspace byte offsets ----
#define WT_OFF 0              // Wt bf16 [3][256 n][256 k]          (384 KB)
#define Q_OFF 393216          // Q' bf16 [16384][256] (pre-scaled)   (8 MB)
#define K_OFF 8781824         // Kc bf16 chunk-permuted (see below)  (8 MB)
#define V_OFF 17170432        // Vc bf16 32-key-permuted             (8 MB)
// Kc: per (b, 16-key chunk) 8KB block; element (key s, dim n) at
//   (n>>5)*512 + ((n>>3)&3)*128 + (s&15)*8 + (n&7)
//   => flash K-frag ds_read_b128 addr = base + kt*1024 + lane*16 (LINEAR).
// Vc: per (b, 32-key chunk) 16KB block; element (key s, dim n) at
//   byte = (n>>4)*1024 + ((s>>2)&3)*256 + (n&15)*16 + ((s>>4)*4 + (s&3))*2
//   => flash PV B-frag (16x16x32) ds_read_b128 addr = base + dt*1024 + lane*16
//   (LINEAR); k=quad*8+j <-> key=(j>>2)*16+quad*4+(j&3) matches concatenated
//   S^T C-frags of two 16-key chunks as the PV A-operand (x32-rate PV).

// ---------------------------------------------------------------------------
// Kernel 1: W [k][n] fp32 -> Wt bf16 [p][n][k]   (unchanged)
// ---------------------------------------------------------------------------
__global__ __launch_bounds__(256) void prep_wt(const float* __restrict__ Wq,
                                               const float* __restrict__ Wk,
                                               const float* __restrict__ Wv,
                                               bf16* __restrict__ Wt) {
  const int idx = blockIdx.x * 256 + threadIdx.x;
  const int p = idx >> 16;
  const int rem = idx & 65535;  // k*256 + n
  const int k = rem >> 8, n = rem & 255;
  const float* W = (p == 0) ? Wq : ((p == 1) ? Wk : Wv);
  Wt[p * 65536 + n * 256 + k] = (bf16)W[rem];
}

// ---------------------------------------------------------------------------
// Kernel 2: weight-stationary QKV projection (unchanged from R4).
// ---------------------------------------------------------------------------
__global__ __launch_bounds__(256, 3) void proj_qkv(const float* __restrict__ x,
                                                   const float* __restrict__ bq,
                                                   const float* __restrict__ bk,
                                                   const float* __restrict__ bv,
                                                   char* __restrict__ ws0) {
  __shared__ __align__(16) char smem[40960];  // 2 x 16KB swizzled x-tile + 8KB out
  const bf16* Wt = (const bf16*)(ws0 + WT_OFF);
  bf16* Qo = (bf16*)(ws0 + Q_OFF);
  bf16* Ko = (bf16*)(ws0 + K_OFF);
  bf16* Vc = (bf16*)(ws0 + V_OFF);
  const int t = threadIdx.x;
  const int lane = t & 63, w = t >> 6, l16 = lane & 15, quad = lane >> 4;
  const int fam = blockIdx.x % 6;    // consecutive blocks: same rows, all 6
  const int rgroup = blockIdx.x / 6; // families -> x tiles L2/L3-hot across XCDs
  const int p = fam >> 1, ch = fam & 1;
  const float* bias = (p == 0) ? bq : ((p == 1) ? bk : bv);
  const float sc = (p == 0) ? 0.09016844005556021f : 1.0f;  // log2e/16

  // ---- persistent B-frags: wave owns 32 cols (2 x 16), full K=256 ----
  const int nl = w * 32 + l16;  // block-local col, nt adds +16
  bf16x8 bfr[2][8];
#pragma unroll
  for (int nt = 0; nt < 2; ++nt)
#pragma unroll
    for (int kt = 0; kt < 8; ++kt)
      bfr[nt][kt] = *(const bf16x8*)&Wt[p * 65536 + (ch * 128 + nl + nt * 16) * 256 +
                                        kt * 32 + quad * 8];
  float bias2[2];
#pragma unroll
  for (int nt = 0; nt < 2; ++nt) bias2[nt] = bias[ch * 128 + nl + nt * 16];

  const int row0 = rgroup * 128;  // global first row of this block
  char* outL = smem + 32768;

  float4 xr[4][2];  // in-flight x tile (32 rows x 256 fp32 / 256 thr = 128B/thr)
#define STAGE_LOAD(tile)                                                        \
  {                                                                             \
    const float* xp = x + (row0 + (tile) * 32) * 256;                           \
    _Pragma("unroll") for (int i = 0; i < 4; ++i) {                             \
      const int u2 = i * 256 + t, row = u2 >> 5, col8 = (u2 & 31) * 8;          \
      xr[i][0] = *(const float4*)&xp[row * 256 + col8];                         \
      xr[i][1] = *(const float4*)&xp[row * 256 + col8 + 4];                     \
    }                                                                           \
  }
#define STAGE_WRITE(buf)                                                        \
  {                                                                             \
    _Pragma("unroll") for (int i = 0; i < 4; ++i) {                             \
      const int u2 = i * 256 + t, row = u2 >> 5, col8 = (u2 & 31) * 8;          \
      const float* f0 = (const float*)&xr[i][0];                                \
      const float* f1 = (const float*)&xr[i][1];                                \
      bf16x8 h;                                                                 \
      _Pragma("unroll") for (int j = 0; j < 4; ++j) {                           \
        h[j] = (bf16)f0[j];                                                     \
        h[4 + j] = (bf16)f1[j];                                                 \
      }                                                                         \
      *(bf16x8*)&smem[(buf) * 16384 + row * 512 +                               \
                      ((col8 * 2) ^ ((row & 7) << 4))] = h;                     \
    }                                                                           \
  }

  STAGE_LOAD(0);
  STAGE_WRITE(0);
  __syncthreads();

  int cur = 0;
  for (int tt = 0; tt < 4; ++tt) {
    if (tt < 3) STAGE_LOAD(tt + 1);  // issue early; consumed after next barrier

    // ---- 32 MFMAs from swizzled LDS A-frags + register B-frags ----
    f32x4 acc[2][2];
#pragma unroll
    for (int rs = 0; rs < 2; ++rs)
#pragma unroll
      for (int nt = 0; nt < 2; ++nt) acc[rs][nt] = f32x4{0.f, 0.f, 0.f, 0.f};
    const char* xb = smem + cur * 16384;
#pragma unroll
    for (int rs = 0; rs < 2; ++rs) {
      const int row = rs * 16 + l16;
#pragma unroll
      for (int kt = 0; kt < 8; ++kt) {
        const bf16x8 a = *(const bf16x8*)(xb + row * 512 +
                                          ((kt * 64 + quad * 16) ^ ((l16 & 7) << 4)));
        acc[rs][0] = MFMA_X32(a, bfr[0][kt], acc[rs][0]);
        acc[rs][1] = MFMA_X32(a, bfr[1][kt], acc[rs][1]);
      }
    }
    __syncthreads();  // prev tile's coop-write reads of outL complete

    // ---- scatter acc into outL in the flash permutation ----
#pragma unroll
    for (int rs = 0; rs < 2; ++rs)
#pragma unroll
      for (int nt = 0; nt < 2; ++nt)
#pragma unroll
        for (int r = 0; r < 4; ++r) {
          const int sl = rs * 16 + quad * 4 + r;  // C/D: row = quad*4+r
          const int nn = nl + nt * 16;            // block-local col 0..127
          const bf16 hv = (bf16)((acc[rs][nt][r] + bias2[nt]) * sc);
          int pos;
          if (p == 0)
            pos = sl * 128 + nn;
          else if (p == 1)
            pos = (sl >> 4) * 2048 + (nn >> 5) * 512 + ((nn >> 3) & 3) * 128 +
                  (sl & 15) * 8 + (nn & 7);
          else  // 32-key Vc permutation (element offset within 32x128 half)
            pos = (nn >> 4) * 512 + ((sl >> 2) & 3) * 128 + (nn & 15) * 8 +
                  (sl >> 4) * 4 + (sl & 3);
          *(bf16*)(outL + pos * 2) = hv;
        }
    if (tt < 3) STAGE_WRITE(cur ^ 1);
    __syncthreads();  // scatter + next x-tile visible to all waves

    // ---- coalesced 32B/thread write of the 8KB out tile ----
    const int rowg = row0 + tt * 32;
    if (p == 0) {
      const int row = t >> 3, cb = (t & 7) * 32;
      const float4 v0 = *(const float4*)(outL + row * 256 + cb);
      const float4 v1 = *(const float4*)(outL + row * 256 + cb + 16);
      char* dst = (char*)Qo + (rowg + row) * 512 + ch * 256 + cb;
      *(float4*)dst = v0;
      *(float4*)(dst + 16) = v1;
    } else if (p == 1) {
      const int b2 = rowg >> 11, s0 = rowg & 2047;
      char* dst = (char*)Ko + b2 * 1048576 + ((s0 >> 4) + (t >> 7)) * 8192 +
                  ch * 4096 + (t & 127) * 32;
      const float4 v0 = *(const float4*)(outL + t * 32);
      const float4 v1 = *(const float4*)(outL + t * 32 + 16);
      *(float4*)dst = v0;
      *(float4*)(dst + 16) = v1;
    } else {
      const int b2 = rowg >> 11, s0 = rowg & 2047;
      char* dst = (char*)Vc + b2 * 1048576 + (s0 >> 5) * 16384 + ch * 8192 + t * 32;
      const float4 v0 = *(const float4*)(outL + t * 32);
      const float4 v1 = *(const float4*)(outL + t * 32 + 16);
      *(float4*)dst = v0;
      *(float4*)(dst + 16) = v1;
    }
    cur ^= 1;
  }
#undef STAGE_LOAD
#undef STAGE_WRITE
}

// ---------------------------------------------------------------------------
// Kernel 3 (R5 resubmit): flash attention, counted-vmcnt pipelined barriers.
// Arithmetic identical to R4 (32-key softmax, x32 PV, defer-max).
// K: 3 rotating 32KB buffers (chunk c -> buf c%3), staged 2 phases ahead;
//    K(c+2) issued at phase-c entry lands in K(c-1)'s buffer, whose reads
//    were fenced by this entry's barrier.
// V: single 64KB buffer at VBASE; V(p) issued at even-phase entry (BEFORE
//    K(c+2) -- age order is what makes vmcnt(4) sufficient), read at end of
//    odd phase; overwrite of V(p-1) fenced by the even entry barrier.
// vmcnt ledger (per wave; K stage = 4 loads, V stage = 8):
//   even entry: queue [K(2p) <=4, K(2p+1) 4] -> vmcnt(4) completes K(2p).
//   odd entry:  queue [K(2p+1) 4, V(p) 8, K(2p+2) 4] -> vmcnt(4) completes
//               K(2p+1) and V(p).  Phases 0 and 31 use vmcnt(0).
// LDS = 3*32K (K) + 64K (V) = 160 KiB. Merge scratch overlays staging
// buffers after a post-loop __syncthreads.
// ---------------------------------------------------------------------------
#define KBUFSZ 32768u
#define VBASE 98304u
#define SLOT_SZ 16640  // merge slot: 16 rows * 260 floats (conflict-free)

__global__ __launch_bounds__(512, 2) void flash_attn(const char* __restrict__ ws0,
                                                     float* __restrict__ out) {
  __shared__ __align__(1024) char smem[163840];  // 3x32KB K + 64KB V
  const bf16* Qp = (const bf16*)(ws0 + Q_OFF);
  const int t = threadIdx.x;
  const int lane = t & 63, w = t >> 6;
  const int l16 = lane & 15, quad = lane >> 4;
  const int qs = w & 1, kq = w >> 1;
  const int b = blockIdx.x & 7;  // batch == XCD round-robin: K/V L2-resident
  const int qt = blockIdx.x >> 3;
  const int qrow0 = b * 2048 + qt * 64 + qs * 32;

  bf16x8 qf[2][8];
#pragma unroll
  for (int qsub = 0; qsub < 2; ++qsub)
#pragma unroll
    for (int kt = 0; kt < 8; ++kt)
      qf[qsub][kt] =
          *(const bf16x8*)&Qp[(qrow0 + qsub * 16 + l16) * 256 + kt * 32 + quad * 8];

  f32x4 o[2][16];
#pragma unroll
  for (int qsub = 0; qsub < 2; ++qsub)
#pragma unroll
    for (int dt = 0; dt < 16; ++dt) o[qsub][dt] = f32x4{0.f, 0.f, 0.f, 0.f};
  float m_[2] = {-1e30f, -1e30f}, l_[2] = {0.f, 0.f};

  // K staging: 32 units/chunk (8 waves x 4), 1KB each; 16-key chunk = 8KB/kq.
  unsigned goffK[4], loffK[4];
#pragma unroll
  for (int i = 0; i < 4; ++i) {
    const int u = w * 4 + i;
    const int kq2 = u >> 3, e = u & 7;
    goffK[i] = (unsigned)K_OFF + b * 1048576u + kq2 * 262144u + e * 1024u + lane * 16u;
    loffK[i] = kq2 * 8192u + e * 1024u;
  }
  // V staging: 64 units/32-key block (8 waves x 8), 1KB each; 16KB/kq.
  unsigned goffV[8], loffV[8];
#pragma unroll
  for (int i = 0; i < 8; ++i) {
    const int u = w * 8 + i;
    const int kqv = u >> 4, e = u & 15;
    goffV[i] = (unsigned)V_OFF + b * 1048576u + kqv * 262144u + e * 1024u + lane * 16u;
    loffV[i] = kqv * 16384u + e * 1024u;
  }

#define STAGE_K(S, BUF)                                                        \
  {                                                                            \
    _Pragma("unroll") for (int i = 0; i < 4; ++i)                              \
        gll16(ws0 + goffK[i] + (unsigned)(S) * 8192u,                          \
              smem + (unsigned)(BUF) * KBUFSZ + loffK[i]);                     \
  }
#define STAGE_V(P)                                                             \
  {                                                                            \
    _Pragma("unroll") for (int i = 0; i < 8; ++i)                              \
        gll16(ws0 + goffV[i] + (unsigned)(P) * 16384u, smem + VBASE + loffV[i]); \
  }
#define QK_STEP(BUF, KC)                                                       \
  {                                                                            \
    const char* kb = smem + (unsigned)(BUF) * KBUFSZ + kq * 8192 + lane * 16;  \
    __builtin_amdgcn_s_setprio(1);                                             \
    _Pragma("unroll") for (int kt = 0; kt < 8; ++kt) {                         \
      const bf16x8 kf = *(const bf16x8*)(kb + kt * 1024);                      \
      sfr[0][KC] = MFMA_X32(kf, qf[0][kt], sfr[0][KC]);                        \
      sfr[1][KC] = MFMA_X32(kf, qf[1][kt], sfr[1][KC]);                        \
    }                                                                          \
    __builtin_amdgcn_s_setprio(0);                                             \
  }

  // Prologue: K0 -> buf0, K1 -> buf1. (Q-frag loads are older; E0's vmcnt(0)
  // covers them too.)
  STAGE_K(0, 0);
  STAGE_K(1, 1);

  int b0 = 0, b1 = 1, b2 = 2;  // buffers of chunks c, c+1, c+2 (c = 2p)
  for (int p = 0; p < 16; ++p) {
    f32x4 sfr[2][2];
#pragma unroll
    for (int qsub = 0; qsub < 2; ++qsub)
#pragma unroll
      for (int kc = 0; kc < 2; ++kc) sfr[qsub][kc] = f32x4{0.f, 0.f, 0.f, 0.f};

    // ---- even phase entry E_{2p}: need K(2p); queue [K(2p), K(2p+1)] ----
    if (p == 0) {
      WAIT_BARRIER(0)  // also drains Q-frag loads; once only
    } else {
      WAIT_BARRIER(4)
    }
    STAGE_V(p);  // V first: older than K(2p+2) so odd-entry vmcnt(4) frees it
    asm volatile("" ::: "memory");  // pin V-before-K issue age order
    if (p < 15) STAGE_K(2 * p + 2, b2);
    QK_STEP(b0, 0);

    // ---- odd phase entry E_{2p+1}: need K(2p+1) AND V(p);
    //      queue [K(2p+1), V(p), K(2p+2)] -> vmcnt(4) ----
    if (p < 15) {
      WAIT_BARRIER(4)
      STAGE_K(2 * p + 3, b0);  // buf of K(2p): reads fenced by this barrier
    } else {
      WAIT_BARRIER(0)  // final phase: drain (nothing left to prefetch)
    }
    QK_STEP(b1, 1);

    // ---- online softmax over 32 keys (log2; q=l16, key=kc*16+quad*4+r) ----
    bf16x8 pa[2];
#pragma unroll
    for (int qsub = 0; qsub < 2; ++qsub) {
      const f32x4 sA = sfr[qsub][0], sB = sfr[qsub][1];
      float cm = fmaxf(fmaxf(fmaxf(sA[0], sA[1]), fmaxf(sA[2], sA[3])),
                       fmaxf(fmaxf(sB[0], sB[1]), fmaxf(sB[2], sB[3])));
      cm = fmaxf(cm, __shfl_xor(cm, 16));
      cm = fmaxf(cm, __shfl_xor(cm, 32));
      const float mold = m_[qsub];
      const bool upd = __any(cm > mold + 6.0f);  // defer-max: P <= 2^6
      float Mref = mold;
      if (upd) Mref = fmaxf(mold, cm);
      float ps = 0.f;
#pragma unroll
      for (int r = 0; r < 4; ++r) {
        const bf16 p0 = (bf16)fast_exp2(sA[r] - Mref);
        const bf16 p1 = (bf16)fast_exp2(sB[r] - Mref);
        pa[qsub][r] = p0;
        pa[qsub][4 + r] = p1;
        ps += (float)p0 + (float)p1;  // sum ROUNDED p for O/l consistency
      }
      ps += __shfl_xor(ps, 16);
      ps += __shfl_xor(ps, 32);
      if (upd) {
        const float al = fast_exp2(mold - Mref);
        m_[qsub] = Mref;
        l_[qsub] = l_[qsub] * al + ps;
        float ar[4];
#pragma unroll
        for (int r = 0; r < 4; ++r)
          ar[r] = __shfl(al, (quad << 4) + (quad << 2) + r);
#pragma unroll
        for (int dt = 0; dt < 16; ++dt)
#pragma unroll
          for (int r = 0; r < 4; ++r) o[qsub][dt][r] *= ar[r];
      } else {
        l_[qsub] += ps;
      }
    }

    // ---- O += P · V: 32-key x32 MFMAs; V b128 LINEAR (resident per E_{2p+1}) --
    const char* vb = smem + VBASE + kq * 16384 + lane * 16;
    __builtin_amdgcn_s_setprio(1);
#pragma unroll
    for (int dt = 0; dt < 16; ++dt) {
      const bf16x8 vf = *(const bf16x8*)(vb + dt * 1024);
      o[0][dt] = MFMA_X32(pa[0], vf, o[0][dt]);
      o[1][dt] = MFMA_X32(pa[1], vf, o[1][dt]);
    }
    __builtin_amdgcn_s_setprio(0);

    // rotate buffers: chunks 2p+2, 2p+3, 2p+4 -> b2, b0, b1
    const int nb0 = b2, nb1 = b0, nb2 = b1;
    b0 = nb0;
    b1 = nb1;
    b2 = nb2;
  }
#undef STAGE_K
#undef STAGE_V
#undef QK_STEP

  __syncthreads();  // ALL PV/QK reads done before merge overlays staging LDS

  // ---- merge 4 kq partials (slots + mlf overlay staging buffers) ----
  float* mlf = (float*)(smem + 133120);
  if (quad == 0) {
#pragma unroll
    for (int qsub = 0; qsub < 2; ++qsub) {
      const int base = ((kq * 2 + qs) * 2 + qsub) * 32;
      mlf[base + l16] = m_[qsub];
      mlf[base + 16 + l16] = l_[qsub];
    }
  }
  __syncthreads();
#pragma unroll
  for (int qsub = 0; qsub < 2; ++qsub) {
    float M = -1e30f, mk[4], lk[4];
#pragma unroll
    for (int k2 = 0; k2 < 4; ++k2) {
      const int base = ((k2 * 2 + qs) * 2 + qsub) * 32;
      mk[k2] = mlf[base + l16];
      lk[k2] = mlf[base + 16 + l16];
      M = fmaxf(M, mk[k2]);
    }
    float L = 0.f;
#pragma unroll
    for (int k2 = 0; k2 < 4; ++k2) L += lk[k2] * fast_exp2(mk[k2] - M);
    const float sg = fast_exp2(m_[qsub] - M) / L;
    float sr[4];
#pragma unroll
    for (int r = 0; r < 4; ++r) sr[r] = __shfl(sg, (quad << 4) + (quad << 2) + r);
#pragma unroll
    for (int dt = 0; dt < 16; ++dt)
#pragma unroll
      for (int r = 0; r < 4; ++r) o[qsub][dt][r] *= sr[r];
  }
  if (kq >= 2) {
#pragma unroll
    for (int qsub = 0; qsub < 2; ++qsub) {
      float* sb = (float*)(smem + ((kq - 2) * 4 + qs * 2 + qsub) * SLOT_SZ);
#pragma unroll
      for (int dt = 0; dt < 16; ++dt)
#pragma unroll
        for (int r = 0; r < 4; ++r)
          sb[(quad * 4 + r) * 260 + dt * 16 + l16] = o[qsub][dt][r];
    }
  }
  __syncthreads();
  if (kq < 2) {
#pragma unroll
    for (int qsub = 0; qsub < 2; ++qsub) {
      const float* sb = (const float*)(smem + (kq * 4 + qs * 2 + qsub) * SLOT_SZ);
#pragma unroll
      for (int dt = 0; dt < 16; ++dt)
#pragma unroll
        for (int r = 0; r < 4; ++r)
          o[qsub][dt][r] += sb[(quad * 4 + r) * 260 + dt * 16 + l16];
    }
  }
  __syncthreads();
  if (kq == 1) {
#pragma unroll
    for (int qsub = 0; qsub < 2; ++qsub) {
      float* sb = (float*)(smem + (qs * 2 + qsub) * SLOT_SZ);
#pragma unroll
      for (int dt = 0; dt < 16; ++dt)
#pragma unroll
        for (int r = 0; r < 4; ++r)
          sb[(quad * 4 + r) * 260 + dt * 16 + l16] = o[qsub][dt][r];
    }
  }
  __syncthreads();
  if (kq == 0) {
#pragma unroll
    for (int qsub = 0; qsub < 2; ++qsub) {
      const float* sb = (const float*)(smem + (qs * 2 + qsub) * SLOT_SZ);
#pragma unroll
      for (int dt = 0; dt < 16; ++dt)
#pragma unroll
        for (int r = 0; r < 4; ++r) {
          const float v = o[qsub][dt][r] + sb[(quad * 4 + r) * 260 + dt * 16 + l16];
          out[(qrow0 + qsub * 16 + quad * 4 + r) * 256 + dt * 16 + l16] = v;
        }
    }
  }
}

extern "C" void kernel_launch(void* const* d_in, const int* in_sizes, int n_in,
                              void* d_out, int out_size, void* d_ws,
                              size_t ws_size, hipStream_t stream) {
  const float* x = (const float*)d_in[0];
  const float* Wq = (const float*)d_in[1];
  const float* bq = (const float*)d_in[2];
  const float* Wk = (const float*)d_in[3];
  const float* bk = (const float*)d_in[4];
  const float* Wv = (const float*)d_in[5];
  const float* bv = (const float*)d_in[6];
  float* out = (float*)d_out;
  char* ws = (char*)d_ws;

  prep_wt<<<768, 256, 0, stream>>>(Wq, Wk, Wv, (bf16*)(ws + WT_OFF));
  proj_qkv<<<768, 256, 0, stream>>>(x, bq, bk, bv, ws);
  flash_attn<<<256, 512, 0, stream>>>(ws, out);
}

// Round 7
// 186.937 us; speedup vs baseline: 1.0727x; 1.0727x over previous
//
#include <hip/hip_runtime.h>

typedef __bf16 bf16;
typedef __bf16 bf16x4v __attribute__((ext_vector_type(4)));
typedef __bf16 bf16x8 __attribute__((ext_vector_type(8)));
typedef float f32x4 __attribute__((ext_vector_type(4)));
typedef short s16x4 __attribute__((ext_vector_type(4)));

#define MFMA_X32(A, B, C) __builtin_amdgcn_mfma_f32_16x16x32_bf16(A, B, C, 0, 0, 0)

static __device__ __forceinline__ float fast_exp2(float x) {
  float r;
  asm volatile("v_exp_f32 %0, %1\n\ts_nop 0" : "=v"(r) : "v"(x));
  return r;
}

static __device__ __forceinline__ void gll16(const void* g, void* l) {
  __builtin_amdgcn_global_load_lds(
      (const __attribute__((address_space(1))) void*)g,
      (__attribute__((address_space(3))) void*)l, 16, 0, 0);
}

// ---- workspace byte offsets ----
#define WT_OFF 0              // Wt bf16 [3][256 n][256 k]          (384 KB)
#define Q_OFF 393216          // Q' bf16 [16384][256] (pre-scaled)   (8 MB)
#define K_OFF 8781824         // Kc bf16 chunk-permuted (see below)  (8 MB)
#define V_OFF 17170432        // Vc bf16 32-key-permuted             (8 MB)
// Kc: per (b, 16-key chunk) 8KB block; element (key s, dim n) at
//   (n>>5)*512 + ((n>>3)&3)*128 + (s&15)*8 + (n&7)
//   => flash K-frag ds_read_b128 addr = base + kt*1024 + lane*16 (LINEAR).
// Vc: per (b, 32-key chunk) 16KB block; element (key s, dim n) at
//   byte = (n>>4)*1024 + ((s>>2)&3)*256 + (n&15)*16 + ((s>>4)*4 + (s&3))*2
//   => flash PV B-frag (16x16x32) addr = base + dt*1024 + lane*16 (LINEAR);
//   k=quad*8+j <-> key=(j>>2)*16+quad*4+(j&3) matches the concatenated S^T
//   C-frags of two 16-key chunks as the PV A-operand (x32-rate PV).
//   R7: V is read DIRECTLY global->REGISTERS (coalesced b128, L2-resident,
//   issued in 4-load groups under QK/PV cover). V LDS traffic eliminated;
//   flash LDS bytes per pair halve (384 -> 192 KB/CU) and the intra-pair
//   V barrier disappears (one __syncthreads per 32-key pair, fully covered).

// ---------------------------------------------------------------------------
// Kernel 1: W [k][n] fp32 -> Wt bf16 [p][n][k]   (unchanged)
// ---------------------------------------------------------------------------
__global__ __launch_bounds__(256) void prep_wt(const float* __restrict__ Wq,
                                               const float* __restrict__ Wk,
                                               const float* __restrict__ Wv,
                                               bf16* __restrict__ Wt) {
  const int idx = blockIdx.x * 256 + threadIdx.x;
  const int p = idx >> 16;
  const int rem = idx & 65535;  // k*256 + n
  const int k = rem >> 8, n = rem & 255;
  const float* W = (p == 0) ? Wq : ((p == 1) ? Wk : Wv);
  Wt[p * 65536 + n * 256 + k] = (bf16)W[rem];
}

// ---------------------------------------------------------------------------
// Kernel 2: weight-stationary QKV projection (unchanged from R4).
// ---------------------------------------------------------------------------
__global__ __launch_bounds__(256, 3) void proj_qkv(const float* __restrict__ x,
                                                   const float* __restrict__ bq,
                                                   const float* __restrict__ bk,
                                                   const float* __restrict__ bv,
                                                   char* __restrict__ ws0) {
  __shared__ __align__(16) char smem[40960];  // 2 x 16KB swizzled x-tile + 8KB out
  const bf16* Wt = (const bf16*)(ws0 + WT_OFF);
  bf16* Qo = (bf16*)(ws0 + Q_OFF);
  bf16* Ko = (bf16*)(ws0 + K_OFF);
  bf16* Vc = (bf16*)(ws0 + V_OFF);
  const int t = threadIdx.x;
  const int lane = t & 63, w = t >> 6, l16 = lane & 15, quad = lane >> 4;
  const int fam = blockIdx.x % 6;    // consecutive blocks: same rows, all 6
  const int rgroup = blockIdx.x / 6; // families -> x tiles L2/L3-hot across XCDs
  const int p = fam >> 1, ch = fam & 1;
  const float* bias = (p == 0) ? bq : ((p == 1) ? bk : bv);
  const float sc = (p == 0) ? 0.09016844005556021f : 1.0f;  // log2e/16

  // ---- persistent B-frags: wave owns 32 cols (2 x 16), full K=256 ----
  const int nl = w * 32 + l16;  // block-local col, nt adds +16
  bf16x8 bfr[2][8];
#pragma unroll
  for (int nt = 0; nt < 2; ++nt)
#pragma unroll
    for (int kt = 0; kt < 8; ++kt)
      bfr[nt][kt] = *(const bf16x8*)&Wt[p * 65536 + (ch * 128 + nl + nt * 16) * 256 +
                                        kt * 32 + quad * 8];
  float bias2[2];
#pragma unroll
  for (int nt = 0; nt < 2; ++nt) bias2[nt] = bias[ch * 128 + nl + nt * 16];

  const int row0 = rgroup * 128;  // global first row of this block
  char* outL = smem + 32768;

  float4 xr[4][2];  // in-flight x tile (32 rows x 256 fp32 / 256 thr = 128B/thr)
#define STAGE_LOAD(tile)                                                        \
  {                                                                             \
    const float* xp = x + (row0 + (tile) * 32) * 256;                           \
    _Pragma("unroll") for (int i = 0; i < 4; ++i) {                             \
      const int u2 = i * 256 + t, row = u2 >> 5, col8 = (u2 & 31) * 8;          \
      xr[i][0] = *(const float4*)&xp[row * 256 + col8];                         \
      xr[i][1] = *(const float4*)&xp[row * 256 + col8 + 4];                     \
    }                                                                           \
  }
#define STAGE_WRITE(buf)                                                        \
  {                                                                             \
    _Pragma("unroll") for (int i = 0; i < 4; ++i) {                             \
      const int u2 = i * 256 + t, row = u2 >> 5, col8 = (u2 & 31) * 8;          \
      const float* f0 = (const float*)&xr[i][0];                                \
      const float* f1 = (const float*)&xr[i][1];                                \
      bf16x8 h;                                                                 \
      _Pragma("unroll") for (int j = 0; j < 4; ++j) {                           \
        h[j] = (bf16)f0[j];                                                     \
        h[4 + j] = (bf16)f1[j];                                                 \
      }                                                                         \
      *(bf16x8*)&smem[(buf) * 16384 + row * 512 +                               \
                      ((col8 * 2) ^ ((row & 7) << 4))] = h;                     \
    }                                                                           \
  }

  STAGE_LOAD(0);
  STAGE_WRITE(0);
  __syncthreads();

  int cur = 0;
  for (int tt = 0; tt < 4; ++tt) {
    if (tt < 3) STAGE_LOAD(tt + 1);  // issue early; consumed after next barrier

    // ---- 32 MFMAs from swizzled LDS A-frags + register B-frags ----
    f32x4 acc[2][2];
#pragma unroll
    for (int rs = 0; rs < 2; ++rs)
#pragma unroll
      for (int nt = 0; nt < 2; ++nt) acc[rs][nt] = f32x4{0.f, 0.f, 0.f, 0.f};
    const char* xb = smem + cur * 16384;
#pragma unroll
    for (int rs = 0; rs < 2; ++rs) {
      const int row = rs * 16 + l16;
#pragma unroll
      for (int kt = 0; kt < 8; ++kt) {
        const bf16x8 a = *(const bf16x8*)(xb + row * 512 +
                                          ((kt * 64 + quad * 16) ^ ((l16 & 7) << 4)));
        acc[rs][0] = MFMA_X32(a, bfr[0][kt], acc[rs][0]);
        acc[rs][1] = MFMA_X32(a, bfr[1][kt], acc[rs][1]);
      }
    }
    __syncthreads();  // prev tile's coop-write reads of outL complete

    // ---- scatter acc into outL in the flash permutation ----
#pragma unroll
    for (int rs = 0; rs < 2; ++rs)
#pragma unroll
      for (int nt = 0; nt < 2; ++nt)
#pragma unroll
        for (int r = 0; r < 4; ++r) {
          const int sl = rs * 16 + quad * 4 + r;  // C/D: row = quad*4+r
          const int nn = nl + nt * 16;            // block-local col 0..127
          const bf16 hv = (bf16)((acc[rs][nt][r] + bias2[nt]) * sc);
          int pos;
          if (p == 0)
            pos = sl * 128 + nn;
          else if (p == 1)
            pos = (sl >> 4) * 2048 + (nn >> 5) * 512 + ((nn >> 3) & 3) * 128 +
                  (sl & 15) * 8 + (nn & 7);
          else  // 32-key Vc permutation (element offset within 32x128 half)
            pos = (nn >> 4) * 512 + ((sl >> 2) & 3) * 128 + (nn & 15) * 8 +
                  (sl >> 4) * 4 + (sl & 3);
          *(bf16*)(outL + pos * 2) = hv;
        }
    if (tt < 3) STAGE_WRITE(cur ^ 1);
    __syncthreads();  // scatter + next x-tile visible to all waves

    // ---- coalesced 32B/thread write of the 8KB out tile ----
    const int rowg = row0 + tt * 32;
    if (p == 0) {
      const int row = t >> 3, cb = (t & 7) * 32;
      const float4 v0 = *(const float4*)(outL + row * 256 + cb);
      const float4 v1 = *(const float4*)(outL + row * 256 + cb + 16);
      char* dst = (char*)Qo + (rowg + row) * 512 + ch * 256 + cb;
      *(float4*)dst = v0;
      *(float4*)(dst + 16) = v1;
    } else if (p == 1) {
      const int b2 = rowg >> 11, s0 = rowg & 2047;
      char* dst = (char*)Ko + b2 * 1048576 + ((s0 >> 4) + (t >> 7)) * 8192 +
                  ch * 4096 + (t & 127) * 32;
      const float4 v0 = *(const float4*)(outL + t * 32);
      const float4 v1 = *(const float4*)(outL + t * 32 + 16);
      *(float4*)dst = v0;
      *(float4*)(dst + 16) = v1;
    } else {
      const int b2 = rowg >> 11, s0 = rowg & 2047;
      char* dst = (char*)Vc + b2 * 1048576 + (s0 >> 5) * 16384 + ch * 8192 + t * 32;
      const float4 v0 = *(const float4*)(outL + t * 32);
      const float4 v1 = *(const float4*)(outL + t * 32 + 16);
      *(float4*)dst = v0;
      *(float4*)(dst + 16) = v1;
    }
    cur ^= 1;
  }
#undef STAGE_LOAD
#undef STAGE_WRITE
}

// ---------------------------------------------------------------------------
// Kernel 3 (R7): flash attention. R4 arithmetic; V in REGISTERS; K pair-
// staged double buffer; ONE drain barrier per 32-key pair (fully covered).
// - K: pair (2 chunks, 64KB) staged one full pair ahead into buf (p+1)&1;
//   the pair-entry __syncthreads' vmcnt(0) drain has a whole pair (~3-4K cyc)
//   of cover -> effectively free, no vmcnt games (R6's counted-vmcnt hurt).
// - V: 16 b128 coalesced global loads/wave/pair (L2-resident, lane-linear by
//   Vc construction), in 4-load groups: g1,g2 at pair start (QK cover),
//   g3 after PV-g1, g4 after PV-g2. Peak +32 VGPR.
// - wave-uniform staging offsets forced to SGPR via readfirstlane (frees
//   ~24 VGPR so vr fits the 128-VGPR/2-wave budget; WRITE_SIZE = spill canary)
// ---------------------------------------------------------------------------
#define SLOT_SZ 16640  // merge slot: 16 rows * 260 floats (conflict-free)

__global__ __launch_bounds__(512, 2) void flash_attn(const char* __restrict__ ws0,
                                                     float* __restrict__ out) {
  __shared__ __align__(1024) char smem[135168];  // 2 x 64KB K pair bufs + merge
  const bf16* Qp = (const bf16*)(ws0 + Q_OFF);
  const int t = threadIdx.x;
  const int lane = t & 63;
  const int w = __builtin_amdgcn_readfirstlane(t >> 6);  // wave id -> SGPR
  const int l16 = lane & 15, quad = lane >> 4;
  const int qs = w & 1, kq = w >> 1;  // SGPR
  const int b = blockIdx.x & 7;  // batch == XCD round-robin: K/V L2-resident
  const int qt = blockIdx.x >> 3;
  const int qrow0 = b * 2048 + qt * 64 + qs * 32;

  bf16x8 qf[2][8];
#pragma unroll
  for (int qsub = 0; qsub < 2; ++qsub)
#pragma unroll
    for (int kt = 0; kt < 8; ++kt)
      qf[qsub][kt] =
          *(const bf16x8*)&Qp[(qrow0 + qsub * 16 + l16) * 256 + kt * 32 + quad * 8];

  f32x4 o[2][16];
#pragma unroll
  for (int qsub = 0; qsub < 2; ++qsub)
#pragma unroll
    for (int dt = 0; dt < 16; ++dt) o[qsub][dt] = f32x4{0.f, 0.f, 0.f, 0.f};
  float m_[2] = {-1e30f, -1e30f}, l_[2] = {0.f, 0.f};

  const unsigned lane16 = (unsigned)lane * 16u;  // only per-lane address term
  // K staging: wave-uniform (SGPR) base offsets; 4 units/wave/chunk.
  unsigned gK[4], lK[4];
#pragma unroll
  for (int i = 0; i < 4; ++i) {
    const int u = w * 4 + i;  // SGPR
    const int kq2 = u >> 3, e = u & 7;
    gK[i] = (unsigned)K_OFF + (unsigned)b * 1048576u + (unsigned)kq2 * 262144u +
            (unsigned)e * 1024u;
    lK[i] = (unsigned)kq2 * 8192u + (unsigned)e * 1024u;
  }
  // V: direct global->reg; per-wave base (SGPR parts + lane16).
  const char* vg0 = ws0 + (unsigned)V_OFF + (unsigned)b * 1048576u +
                    (unsigned)kq * 262144u + lane16;

#define STAGE_PAIR(Q)                                                          \
  {                                                                            \
    _Pragma("unroll") for (int h = 0; h < 2; ++h)                              \
        _Pragma("unroll") for (int i = 0; i < 4; ++i)                          \
        gll16(ws0 + gK[i] + (unsigned)(2 * (Q) + h) * 8192u + lane16,          \
              smem + (unsigned)((Q) & 1) * 65536u + (unsigned)h * 32768u +     \
                  lK[i]);                                                      \
  }
#define QK_STEP(KOFFB, KC)                                                     \
  {                                                                            \
    __builtin_amdgcn_s_setprio(1);                                             \
    _Pragma("unroll") for (int kt = 0; kt < 8; ++kt) {                         \
      const bf16x8 kf = *(const bf16x8*)(kb + (KOFFB) + kt * 1024);            \
      sfr[0][KC] = MFMA_X32(kf, qf[0][kt], sfr[0][KC]);                        \
      sfr[1][KC] = MFMA_X32(kf, qf[1][kt], sfr[1][KC]);                        \
    }                                                                          \
    __builtin_amdgcn_s_setprio(0);                                             \
  }

  STAGE_PAIR(0);  // prologue (drained, with qf loads, at first barrier)

  for (int p = 0; p < 16; ++p) {
    __syncthreads();  // K pair p resident (staged a full pair ago: free drain)
    const char* kb = smem + (unsigned)(p & 1) * 65536u + (unsigned)kq * 8192u +
                     lane16;
    const char* vg = vg0 + (unsigned)p * 16384u;

    bf16x8 vr[16];  // V fragments, static-indexed groups
#pragma unroll
    for (int dt = 0; dt < 4; ++dt)  // g1: full QK+softmax cover
      vr[dt] = *(const bf16x8*)(vg + dt * 1024);
#pragma unroll
    for (int dt = 4; dt < 8; ++dt)  // g2
      vr[dt] = *(const bf16x8*)(vg + dt * 1024);
    if (p < 15) STAGE_PAIR(p + 1);  // in flight across the whole pair

    f32x4 sfr[2][2];
#pragma unroll
    for (int qsub = 0; qsub < 2; ++qsub)
#pragma unroll
      for (int kc = 0; kc < 2; ++kc) sfr[qsub][kc] = f32x4{0.f, 0.f, 0.f, 0.f};
    QK_STEP(0, 0);       // chunk 2p
    QK_STEP(32768, 1);   // chunk 2p+1

    // ---- online softmax over 32 keys (log2; q=l16, key=kc*16+quad*4+r) ----
    bf16x8 pa[2];
#pragma unroll
    for (int qsub = 0; qsub < 2; ++qsub) {
      const f32x4 sA = sfr[qsub][0], sB = sfr[qsub][1];
      float cm = fmaxf(fmaxf(fmaxf(sA[0], sA[1]), fmaxf(sA[2], sA[3])),
                       fmaxf(fmaxf(sB[0], sB[1]), fmaxf(sB[2], sB[3])));
      cm = fmaxf(cm, __shfl_xor(cm, 16));
      cm = fmaxf(cm, __shfl_xor(cm, 32));
      const float mold = m_[qsub];
      const bool upd = __any(cm > mold + 6.0f);  // defer-max: P <= 2^6
      float Mref = mold;
      if (upd) Mref = fmaxf(mold, cm);
      float ps = 0.f;
#pragma unroll
      for (int r = 0; r < 4; ++r) {
        const bf16 p0 = (bf16)fast_exp2(sA[r] - Mref);
        const bf16 p1 = (bf16)fast_exp2(sB[r] - Mref);
        pa[qsub][r] = p0;
        pa[qsub][4 + r] = p1;
        ps += (float)p0 + (float)p1;  // sum ROUNDED p for O/l consistency
      }
      ps += __shfl_xor(ps, 16);
      ps += __shfl_xor(ps, 32);
      if (upd) {
        const float al = fast_exp2(mold - Mref);
        m_[qsub] = Mref;
        l_[qsub] = l_[qsub] * al + ps;
        float ar[4];
#pragma unroll
        for (int r = 0; r < 4; ++r)
          ar[r] = __shfl(al, (quad << 4) + (quad << 2) + r);
#pragma unroll
        for (int dt = 0; dt < 16; ++dt)
#pragma unroll
          for (int r = 0; r < 4; ++r) o[qsub][dt][r] *= ar[r];
      } else {
        l_[qsub] += ps;
      }
    }

    // ---- O += P · V from registers; staggered V group issue ----
    __builtin_amdgcn_s_setprio(1);
#pragma unroll
    for (int dt = 0; dt < 4; ++dt) {  // consume g1
      o[0][dt] = MFMA_X32(pa[0], vr[dt], o[0][dt]);
      o[1][dt] = MFMA_X32(pa[1], vr[dt], o[1][dt]);
    }
#pragma unroll
    for (int dt = 8; dt < 12; ++dt)  // issue g3 (covered by PV-g2)
      vr[dt] = *(const bf16x8*)(vg + dt * 1024);
#pragma unroll
    for (int dt = 4; dt < 8; ++dt) {  // consume g2
      o[0][dt] = MFMA_X32(pa[0], vr[dt], o[0][dt]);
      o[1][dt] = MFMA_X32(pa[1], vr[dt], o[1][dt]);
    }
#pragma unroll
    for (int dt = 12; dt < 16; ++dt)  // issue g4 (covered by PV-g3)
      vr[dt] = *(const bf16x8*)(vg + dt * 1024);
#pragma unroll
    for (int dt = 8; dt < 12; ++dt) {  // consume g3
      o[0][dt] = MFMA_X32(pa[0], vr[dt], o[0][dt]);
      o[1][dt] = MFMA_X32(pa[1], vr[dt], o[1][dt]);
    }
#pragma unroll
    for (int dt = 12; dt < 16; ++dt) {  // consume g4
      o[0][dt] = MFMA_X32(pa[0], vr[dt], o[0][dt]);
      o[1][dt] = MFMA_X32(pa[1], vr[dt], o[1][dt]);
    }
    __builtin_amdgcn_s_setprio(0);
  }
#undef STAGE_PAIR
#undef QK_STEP

  __syncthreads();  // all QK reads done before merge overlays K buffers

  // ---- merge 4 kq partials (slots overlay K buffers; mlf beyond) ----
  float* mlf = (float*)(smem + 133120);
  if (quad == 0) {
#pragma unroll
    for (int qsub = 0; qsub < 2; ++qsub) {
      const int base = ((kq * 2 + qs) * 2 + qsub) * 32;
      mlf[base + l16] = m_[qsub];
      mlf[base + 16 + l16] = l_[qsub];
    }
  }
  __syncthreads();
#pragma unroll
  for (int qsub = 0; qsub < 2; ++qsub) {
    float M = -1e30f, mk[4], lk[4];
#pragma unroll
    for (int k2 = 0; k2 < 4; ++k2) {
      const int base = ((k2 * 2 + qs) * 2 + qsub) * 32;
      mk[k2] = mlf[base + l16];
      lk[k2] = mlf[base + 16 + l16];
      M = fmaxf(M, mk[k2]);
    }
    float L = 0.f;
#pragma unroll
    for (int k2 = 0; k2 < 4; ++k2) L += lk[k2] * fast_exp2(mk[k2] - M);
    const float sg = fast_exp2(m_[qsub] - M) / L;
    float sr[4];
#pragma unroll
    for (int r = 0; r < 4; ++r) sr[r] = __shfl(sg, (quad << 4) + (quad << 2) + r);
#pragma unroll
    for (int dt = 0; dt < 16; ++dt)
#pragma unroll
      for (int r = 0; r < 4; ++r) o[qsub][dt][r] *= sr[r];
  }
  if (kq >= 2) {
#pragma unroll
    for (int qsub = 0; qsub < 2; ++qsub) {
      float* sb = (float*)(smem + ((kq - 2) * 4 + qs * 2 + qsub) * SLOT_SZ);
#pragma unroll
      for (int dt = 0; dt < 16; ++dt)
#pragma unroll
        for (int r = 0; r < 4; ++r)
          sb[(quad * 4 + r) * 260 + dt * 16 + l16] = o[qsub][dt][r];
    }
  }
  __syncthreads();
  if (kq < 2) {
#pragma unroll
    for (int qsub = 0; qsub < 2; ++qsub) {
      const float* sb = (const float*)(smem + (kq * 4 + qs * 2 + qsub) * SLOT_SZ);
#pragma unroll
      for (int dt = 0; dt < 16; ++dt)
#pragma unroll
        for (int r = 0; r < 4; ++r)
          o[qsub][dt][r] += sb[(quad * 4 + r) * 260 + dt * 16 + l16];
    }
  }
  __syncthreads();
  if (kq == 1) {
#pragma unroll
    for (int qsub = 0; qsub < 2; ++qsub) {
      float* sb = (float*)(smem + (qs * 2 + qsub) * SLOT_SZ);
#pragma unroll
      for (int dt = 0; dt < 16; ++dt)
#pragma unroll
        for (int r = 0; r < 4; ++r)
          sb[(quad * 4 + r) * 260 + dt * 16 + l16] = o[qsub][dt][r];
    }
  }
  __syncthreads();
  if (kq == 0) {
#pragma unroll
    for (int qsub = 0; qsub < 2; ++qsub) {
      const float* sb = (const float*)(smem + (qs * 2 + qsub) * SLOT_SZ);
#pragma unroll
      for (int dt = 0; dt < 16; ++dt)
#pragma unroll
        for (int r = 0; r < 4; ++r) {
          const float v = o[qsub][dt][r] + sb[(quad * 4 + r) * 260 + dt * 16 + l16];
          out[(qrow0 + qsub * 16 + quad * 4 + r) * 256 + dt * 16 + l16] = v;
        }
    }
  }
}

extern "C" void kernel_launch(void* const* d_in, const int* in_sizes, int n_in,
                              void* d_out, int out_size, void* d_ws,
                              size_t ws_size, hipStream_t stream) {
  const float* x = (const float*)d_in[0];
  const float* Wq = (const float*)d_in[1];
  const float* bq = (const float*)d_in[2];
  const float* Wk = (const float*)d_in[3];
  const float* bk = (const float*)d_in[4];
  const float* Wv = (const float*)d_in[5];
  const float* bv = (const float*)d_in[6];
  float* out = (float*)d_out;
  char* ws = (char*)d_ws;

  prep_wt<<<768, 256, 0, stream>>>(Wq, Wk, Wv, (bf16*)(ws + WT_OFF));
  proj_qkv<<<768, 256, 0, stream>>>(x, bq, bk, bv, ws);
  flash_attn<<<256, 512, 0, stream>>>(ws, out);
}

// Round 8
// 158.539 us; speedup vs baseline: 1.2649x; 1.1791x over previous
//
#include <hip/hip_runtime.h>

typedef __bf16 bf16;
typedef __bf16 bf16x4v __attribute__((ext_vector_type(4)));
typedef __bf16 bf16x8 __attribute__((ext_vector_type(8)));
typedef float f32x4 __attribute__((ext_vector_type(4)));
typedef short s16x4 __attribute__((ext_vector_type(4)));

#define MFMA_X32(A, B, C) __builtin_amdgcn_mfma_f32_16x16x32_bf16(A, B, C, 0, 0, 0)

static __device__ __forceinline__ float fast_exp2(float x) {
  float r;
  asm volatile("v_exp_f32 %0, %1\n\ts_nop 0" : "=v"(r) : "v"(x));
  return r;
}

static __device__ __forceinline__ void gll16(const void* g, void* l) {
  __builtin_amdgcn_global_load_lds(
      (const __attribute__((address_space(1))) void*)g,
      (__attribute__((address_space(3))) void*)l, 16, 0, 0);
}

// ---- workspace byte offsets ----
#define WT_OFF 0              // Wt bf16 [3][256 n][256 k]          (384 KB)
#define Q_OFF 393216          // Q' bf16 [16384][256] (pre-scaled)   (8 MB)
#define K_OFF 8781824         // Kc bf16 chunk-permuted (see below)  (8 MB)
#define V_OFF 17170432        // Vc bf16 32-key-permuted             (8 MB)
// Kc: per (b, 16-key chunk) 8KB block; element (key s, dim n) at
//   (n>>5)*512 + ((n>>3)&3)*128 + (s&15)*8 + (n&7)
//   => flash K-frag ds_read_b128 addr = base + kt*1024 + lane*16 (LINEAR).
// Vc: per (b, 32-key chunk) 16KB block; element (key s, dim n) at
//   byte = (n>>4)*1024 + ((s>>2)&3)*256 + (n&15)*16 + ((s>>4)*4 + (s&3))*2
//   => flash PV B-frag (16x16x32) addr = base + dt*1024 + lane*16 (LINEAR);
//   k=quad*8+j <-> key=(j>>2)*16+quad*4+(j&3) matches the concatenated S^T
//   C-frags of two 16-key chunks as the PV A-operand (x32-rate PV).
// R8: flash staging/barriers/layout are EXACTLY R4 (best measured, 66.6us,
// no spill). Only the softmax cross-lane structure changed (see kernel 3).

// ---------------------------------------------------------------------------
// Kernel 1: W [k][n] fp32 -> Wt bf16 [p][n][k]   (unchanged)
// ---------------------------------------------------------------------------
__global__ __launch_bounds__(256) void prep_wt(const float* __restrict__ Wq,
                                               const float* __restrict__ Wk,
                                               const float* __restrict__ Wv,
                                               bf16* __restrict__ Wt) {
  const int idx = blockIdx.x * 256 + threadIdx.x;
  const int p = idx >> 16;
  const int rem = idx & 65535;  // k*256 + n
  const int k = rem >> 8, n = rem & 255;
  const float* W = (p == 0) ? Wq : ((p == 1) ? Wk : Wv);
  Wt[p * 65536 + n * 256 + k] = (bf16)W[rem];
}

// ---------------------------------------------------------------------------
// Kernel 2: weight-stationary QKV projection (unchanged from R4).
// ---------------------------------------------------------------------------
__global__ __launch_bounds__(256, 3) void proj_qkv(const float* __restrict__ x,
                                                   const float* __restrict__ bq,
                                                   const float* __restrict__ bk,
                                                   const float* __restrict__ bv,
                                                   char* __restrict__ ws0) {
  __shared__ __align__(16) char smem[40960];  // 2 x 16KB swizzled x-tile + 8KB out
  const bf16* Wt = (const bf16*)(ws0 + WT_OFF);
  bf16* Qo = (bf16*)(ws0 + Q_OFF);
  bf16* Ko = (bf16*)(ws0 + K_OFF);
  bf16* Vc = (bf16*)(ws0 + V_OFF);
  const int t = threadIdx.x;
  const int lane = t & 63, w = t >> 6, l16 = lane & 15, quad = lane >> 4;
  const int fam = blockIdx.x % 6;    // consecutive blocks: same rows, all 6
  const int rgroup = blockIdx.x / 6; // families -> x tiles L2/L3-hot across XCDs
  const int p = fam >> 1, ch = fam & 1;
  const float* bias = (p == 0) ? bq : ((p == 1) ? bk : bv);
  const float sc = (p == 0) ? 0.09016844005556021f : 1.0f;  // log2e/16

  // ---- persistent B-frags: wave owns 32 cols (2 x 16), full K=256 ----
  const int nl = w * 32 + l16;  // block-local col, nt adds +16
  bf16x8 bfr[2][8];
#pragma unroll
  for (int nt = 0; nt < 2; ++nt)
#pragma unroll
    for (int kt = 0; kt < 8; ++kt)
      bfr[nt][kt] = *(const bf16x8*)&Wt[p * 65536 + (ch * 128 + nl + nt * 16) * 256 +
                                        kt * 32 + quad * 8];
  float bias2[2];
#pragma unroll
  for (int nt = 0; nt < 2; ++nt) bias2[nt] = bias[ch * 128 + nl + nt * 16];

  const int row0 = rgroup * 128;  // global first row of this block
  char* outL = smem + 32768;

  float4 xr[4][2];  // in-flight x tile (32 rows x 256 fp32 / 256 thr = 128B/thr)
#define STAGE_LOAD(tile)                                                        \
  {                                                                             \
    const float* xp = x + (row0 + (tile) * 32) * 256;                           \
    _Pragma("unroll") for (int i = 0; i < 4; ++i) {                             \
      const int u2 = i * 256 + t, row = u2 >> 5, col8 = (u2 & 31) * 8;          \
      xr[i][0] = *(const float4*)&xp[row * 256 + col8];                         \
      xr[i][1] = *(const float4*)&xp[row * 256 + col8 + 4];                     \
    }                                                                           \
  }
#define STAGE_WRITE(buf)                                                        \
  {                                                                             \
    _Pragma("unroll") for (int i = 0; i < 4; ++i) {                             \
      const int u2 = i * 256 + t, row = u2 >> 5, col8 = (u2 & 31) * 8;          \
      const float* f0 = (const float*)&xr[i][0];                                \
      const float* f1 = (const float*)&xr[i][1];                                \
      bf16x8 h;                                                                 \
      _Pragma("unroll") for (int j = 0; j < 4; ++j) {                           \
        h[j] = (bf16)f0[j];                                                     \
        h[4 + j] = (bf16)f1[j];                                                 \
      }                                                                         \
      *(bf16x8*)&smem[(buf) * 16384 + row * 512 +                               \
                      ((col8 * 2) ^ ((row & 7) << 4))] = h;                     \
    }                                                                           \
  }

  STAGE_LOAD(0);
  STAGE_WRITE(0);
  __syncthreads();

  int cur = 0;
  for (int tt = 0; tt < 4; ++tt) {
    if (tt < 3) STAGE_LOAD(tt + 1);  // issue early; consumed after next barrier

    // ---- 32 MFMAs from swizzled LDS A-frags + register B-frags ----
    f32x4 acc[2][2];
#pragma unroll
    for (int rs = 0; rs < 2; ++rs)
#pragma unroll
      for (int nt = 0; nt < 2; ++nt) acc[rs][nt] = f32x4{0.f, 0.f, 0.f, 0.f};
    const char* xb = smem + cur * 16384;
#pragma unroll
    for (int rs = 0; rs < 2; ++rs) {
      const int row = rs * 16 + l16;
#pragma unroll
      for (int kt = 0; kt < 8; ++kt) {
        const bf16x8 a = *(const bf16x8*)(xb + row * 512 +
                                          ((kt * 64 + quad * 16) ^ ((l16 & 7) << 4)));
        acc[rs][0] = MFMA_X32(a, bfr[0][kt], acc[rs][0]);
        acc[rs][1] = MFMA_X32(a, bfr[1][kt], acc[rs][1]);
      }
    }
    __syncthreads();  // prev tile's coop-write reads of outL complete

    // ---- scatter acc into outL in the flash permutation ----
#pragma unroll
    for (int rs = 0; rs < 2; ++rs)
#pragma unroll
      for (int nt = 0; nt < 2; ++nt)
#pragma unroll
        for (int r = 0; r < 4; ++r) {
          const int sl = rs * 16 + quad * 4 + r;  // C/D: row = quad*4+r
          const int nn = nl + nt * 16;            // block-local col 0..127
          const bf16 hv = (bf16)((acc[rs][nt][r] + bias2[nt]) * sc);
          int pos;
          if (p == 0)
            pos = sl * 128 + nn;
          else if (p == 1)
            pos = (sl >> 4) * 2048 + (nn >> 5) * 512 + ((nn >> 3) & 3) * 128 +
                  (sl & 15) * 8 + (nn & 7);
          else  // 32-key Vc permutation (element offset within 32x128 half)
            pos = (nn >> 4) * 512 + ((sl >> 2) & 3) * 128 + (nn & 15) * 8 +
                  (sl >> 4) * 4 + (sl & 3);
          *(bf16*)(outL + pos * 2) = hv;
        }
    if (tt < 3) STAGE_WRITE(cur ^ 1);
    __syncthreads();  // scatter + next x-tile visible to all waves

    // ---- coalesced 32B/thread write of the 8KB out tile ----
    const int rowg = row0 + tt * 32;
    if (p == 0) {
      const int row = t >> 3, cb = (t & 7) * 32;
      const float4 v0 = *(const float4*)(outL + row * 256 + cb);
      const float4 v1 = *(const float4*)(outL + row * 256 + cb + 16);
      char* dst = (char*)Qo + (rowg + row) * 512 + ch * 256 + cb;
      *(float4*)dst = v0;
      *(float4*)(dst + 16) = v1;
    } else if (p == 1) {
      const int b2 = rowg >> 11, s0 = rowg & 2047;
      char* dst = (char*)Ko + b2 * 1048576 + ((s0 >> 4) + (t >> 7)) * 8192 +
                  ch * 4096 + (t & 127) * 32;
      const float4 v0 = *(const float4*)(outL + t * 32);
      const float4 v1 = *(const float4*)(outL + t * 32 + 16);
      *(float4*)dst = v0;
      *(float4*)(dst + 16) = v1;
    } else {
      const int b2 = rowg >> 11, s0 = rowg & 2047;
      char* dst = (char*)Vc + b2 * 1048576 + (s0 >> 5) * 16384 + ch * 8192 + t * 32;
      const float4 v0 = *(const float4*)(outL + t * 32);
      const float4 v1 = *(const float4*)(outL + t * 32 + 16);
      *(float4*)dst = v0;
      *(float4*)(dst + 16) = v1;
    }
    cur ^= 1;
  }
#undef STAGE_LOAD
#undef STAGE_WRITE
}

// ---------------------------------------------------------------------------
// Kernel 3 (R8): EXACT R4 staging/barrier skeleton (best measured: 66.6us,
// VGPR 128, no spill) + cross-lane-free softmax common path:
//  - defer-max test uses per-lane maxima: __any(cml > m+6) == reduced test
//    (OR of subset-maxes == OR of elements). The 2 max-shuffles move inside
//    the rarely-taken upd branch.
//  - l_ accumulates PER-LANE (this lane's 8 keys, rescaled by row-uniform al
//    on upd); quad-reduction done ONCE post-loop (2 shuffles total vs 64).
// Common path per pair: pure VALU (fmax tree + 8 exp) -> overlaps PV MFMAs;
// also removes 128 ds_bpermute ops contending with GLL staging on LDS pipe.
// ---------------------------------------------------------------------------
#define SLOT_SZ 16640  // merge slot: 16 rows * 260 floats (conflict-free)

__global__ __launch_bounds__(512, 2) void flash_attn(const char* __restrict__ ws0,
                                                     float* __restrict__ out) {
  __shared__ __align__(1024) char smem[135168];  // K 2x32KB + V 64KB + scratch
  const bf16* Qp = (const bf16*)(ws0 + Q_OFF);
  const int t = threadIdx.x;
  const int lane = t & 63, w = t >> 6;
  const int l16 = lane & 15, quad = lane >> 4;
  const int qs = w & 1, kq = w >> 1;
  const int b = blockIdx.x & 7;  // batch == XCD round-robin: K/V L2-resident
  const int qt = blockIdx.x >> 3;
  const int qrow0 = b * 2048 + qt * 64 + qs * 32;

  bf16x8 qf[2][8];
#pragma unroll
  for (int qsub = 0; qsub < 2; ++qsub)
#pragma unroll
    for (int kt = 0; kt < 8; ++kt)
      qf[qsub][kt] =
          *(const bf16x8*)&Qp[(qrow0 + qsub * 16 + l16) * 256 + kt * 32 + quad * 8];

  f32x4 o[2][16];
#pragma unroll
  for (int qsub = 0; qsub < 2; ++qsub)
#pragma unroll
    for (int dt = 0; dt < 16; ++dt) o[qsub][dt] = f32x4{0.f, 0.f, 0.f, 0.f};
  float m_[2] = {-1e30f, -1e30f}, l_[2] = {0.f, 0.f};  // l_ is PER-LANE partial

  // K staging: 32 units/step (8 waves x 4), 1KB each; 16-key chunk = 8KB/kq.
  unsigned goffK[4], loffK[4];
#pragma unroll
  for (int i = 0; i < 4; ++i) {
    const int u = w * 4 + i;
    const int kq2 = u >> 3, e = u & 7;
    goffK[i] = (unsigned)K_OFF + b * 1048576u + kq2 * 262144u + e * 1024u + lane * 16u;
    loffK[i] = kq2 * 8192u + e * 1024u;
  }
  // V staging: 64 units/pair (8 waves x 8), 1KB each; 32-key block = 16KB/kq.
  unsigned goffV[8], loffV[8];
#pragma unroll
  for (int i = 0; i < 8; ++i) {
    const int u = w * 8 + i;
    const int kqv = u >> 4, e = u & 15;
    goffV[i] = (unsigned)V_OFF + b * 1048576u + kqv * 262144u + e * 1024u + lane * 16u;
    loffV[i] = 65536u + kqv * 16384u + e * 1024u;
  }

#define STAGE_K(S)                                                             \
  {                                                                            \
    _Pragma("unroll") for (int i = 0; i < 4; ++i)                              \
        gll16(ws0 + goffK[i] + (unsigned)(S) * 8192u,                          \
              smem + (unsigned)(((S) & 1) * 32768) + loffK[i]);                \
  }
#define STAGE_V(P)                                                             \
  {                                                                            \
    _Pragma("unroll") for (int i = 0; i < 8; ++i)                              \
        gll16(ws0 + goffV[i] + (unsigned)(P) * 16384u, smem + loffV[i]);       \
  }
#define QK_STEP(CURK, KC)                                                      \
  {                                                                            \
    const char* kb = smem + (CURK) + kq * 8192 + lane * 16;                    \
    __builtin_amdgcn_s_setprio(1);                                             \
    _Pragma("unroll") for (int kt = 0; kt < 8; ++kt) {                         \
      const bf16x8 kf = *(const bf16x8*)(kb + kt * 1024);                      \
      sfr[0][KC] = MFMA_X32(kf, qf[0][kt], sfr[0][KC]);                        \
      sfr[1][KC] = MFMA_X32(kf, qf[1][kt], sfr[1][KC]);                        \
    }                                                                          \
    __builtin_amdgcn_s_setprio(0);                                             \
  }

  STAGE_K(0);  // prologue

  for (int p = 0; p < 16; ++p) {
    f32x4 sfr[2][2];
#pragma unroll
    for (int qsub = 0; qsub < 2; ++qsub)
#pragma unroll
      for (int kc = 0; kc < 2; ++kc) sfr[qsub][kc] = f32x4{0.f, 0.f, 0.f, 0.f};

    // ---- step 2p: K(2p) resident; stage K(2p+1) + V(p) ----
    __syncthreads();
    STAGE_K(2 * p + 1);
    STAGE_V(p);
    QK_STEP((unsigned)((2 * p) & 1) * 32768u, 0);

    // ---- step 2p+1: K(2p+1) + V(p) resident; stage K(2p+2) ----
    __syncthreads();
    if (p < 15) STAGE_K(2 * p + 2);
    QK_STEP((unsigned)((2 * p + 1) & 1) * 32768u, 1);

    // ---- online softmax over 32 keys (log2; q=l16, key=kc*16+quad*4+r) ----
    // Common path: NO cross-lane ops (see kernel header comment).
    bf16x8 pa[2];
#pragma unroll
    for (int qsub = 0; qsub < 2; ++qsub) {
      const f32x4 sA = sfr[qsub][0], sB = sfr[qsub][1];
      const float cml = fmaxf(fmaxf(fmaxf(sA[0], sA[1]), fmaxf(sA[2], sA[3])),
                              fmaxf(fmaxf(sB[0], sB[1]), fmaxf(sB[2], sB[3])));
      const float mold = m_[qsub];
      if (__builtin_expect(__any(cml > mold + 6.0f), 0)) {  // defer-max (T13)
        float cm = fmaxf(cml, __shfl_xor(cml, 16));
        cm = fmaxf(cm, __shfl_xor(cm, 32));  // row max (quad-replicated)
        const float Mnew = fmaxf(mold, cm);
        const float al = fast_exp2(mold - Mnew);  // row-uniform across quads
        m_[qsub] = Mnew;
        l_[qsub] *= al;  // per-lane partial scales identically
        float ar[4];
#pragma unroll
        for (int r = 0; r < 4; ++r)
          ar[r] = __shfl(al, (quad << 4) + (quad << 2) + r);
#pragma unroll
        for (int dt = 0; dt < 16; ++dt)
#pragma unroll
          for (int r = 0; r < 4; ++r) o[qsub][dt][r] *= ar[r];
      }
      const float Mref = m_[qsub];
      float ps = 0.f;
#pragma unroll
      for (int r = 0; r < 4; ++r) {
        const bf16 p0 = (bf16)fast_exp2(sA[r] - Mref);
        const bf16 p1 = (bf16)fast_exp2(sB[r] - Mref);
        pa[qsub][r] = p0;
        pa[qsub][4 + r] = p1;
        ps += (float)p0 + (float)p1;  // sum ROUNDED p for O/l consistency
      }
      l_[qsub] += ps;  // per-lane; quad-reduced once after the loop
    }

    // ---- O += P · V: 32-key x32 MFMAs; V b128 LINEAR from single buffer ----
    const char* vb = smem + 65536 + kq * 16384 + lane * 16;
    __builtin_amdgcn_s_setprio(1);
#pragma unroll
    for (int dt = 0; dt < 16; ++dt) {
      const bf16x8 vf = *(const bf16x8*)(vb + dt * 1024);
      o[0][dt] = MFMA_X32(pa[0], vf, o[0][dt]);
      o[1][dt] = MFMA_X32(pa[1], vf, o[1][dt]);
    }
    __builtin_amdgcn_s_setprio(0);
  }
#undef STAGE_K
#undef STAGE_V
#undef QK_STEP

  // ---- deferred l quad-reduction: 2 shuffles per qsub, ONCE ----
#pragma unroll
  for (int qsub = 0; qsub < 2; ++qsub) {
    l_[qsub] += __shfl_xor(l_[qsub], 16);
    l_[qsub] += __shfl_xor(l_[qsub], 32);  // row total, quad-replicated
  }

  // ---- merge 4 kq partials (slots overlay staging buffers; reads done) ----
  float* mlf = (float*)(smem + 133120);  // beyond merge slots: no overlap
  if (quad == 0) {
#pragma unroll
    for (int qsub = 0; qsub < 2; ++qsub) {
      const int base = ((kq * 2 + qs) * 2 + qsub) * 32;
      mlf[base + l16] = m_[qsub];
      mlf[base + 16 + l16] = l_[qsub];
    }
  }
  __syncthreads();
#pragma unroll
  for (int qsub = 0; qsub < 2; ++qsub) {
    float M = -1e30f, mk[4], lk[4];
#pragma unroll
    for (int k2 = 0; k2 < 4; ++k2) {
      const int base = ((k2 * 2 + qs) * 2 + qsub) * 32;
      mk[k2] = mlf[base + l16];
      lk[k2] = mlf[base + 16 + l16];
      M = fmaxf(M, mk[k2]);
    }
    float L = 0.f;
#pragma unroll
    for (int k2 = 0; k2 < 4; ++k2) L += lk[k2] * fast_exp2(mk[k2] - M);
    const float sg = fast_exp2(m_[qsub] - M) / L;
    float sr[4];
#pragma unroll
    for (int r = 0; r < 4; ++r) sr[r] = __shfl(sg, (quad << 4) + (quad << 2) + r);
#pragma unroll
    for (int dt = 0; dt < 16; ++dt)
#pragma unroll
      for (int r = 0; r < 4; ++r) o[qsub][dt][r] *= sr[r];
  }
  if (kq >= 2) {
#pragma unroll
    for (int qsub = 0; qsub < 2; ++qsub) {
      float* sb = (float*)(smem + ((kq - 2) * 4 + qs * 2 + qsub) * SLOT_SZ);
#pragma unroll
      for (int dt = 0; dt < 16; ++dt)
#pragma unroll
        for (int r = 0; r < 4; ++r)
          sb[(quad * 4 + r) * 260 + dt * 16 + l16] = o[qsub][dt][r];
    }
  }
  __syncthreads();
  if (kq < 2) {
#pragma unroll
    for (int qsub = 0; qsub < 2; ++qsub) {
      const float* sb = (const float*)(smem + (kq * 4 + qs * 2 + qsub) * SLOT_SZ);
#pragma unroll
      for (int dt = 0; dt < 16; ++dt)
#pragma unroll
        for (int r = 0; r < 4; ++r)
          o[qsub][dt][r] += sb[(quad * 4 + r) * 260 + dt * 16 + l16];
    }
  }
  __syncthreads();
  if (kq == 1) {
#pragma unroll
    for (int qsub = 0; qsub < 2; ++qsub) {
      float* sb = (float*)(smem + (qs * 2 + qsub) * SLOT_SZ);
#pragma unroll
      for (int dt = 0; dt < 16; ++dt)
#pragma unroll
        for (int r = 0; r < 4; ++r)
          sb[(quad * 4 + r) * 260 + dt * 16 + l16] = o[qsub][dt][r];
    }
  }
  __syncthreads();
  if (kq == 0) {
#pragma unroll
    for (int qsub = 0; qsub < 2; ++qsub) {
      const float* sb = (const float*)(smem + (qs * 2 + qsub) * SLOT_SZ);
#pragma unroll
      for (int dt = 0; dt < 16; ++dt)
#pragma unroll
        for (int r = 0; r < 4; ++r) {
          const float v = o[qsub][dt][r] + sb[(quad * 4 + r) * 260 + dt * 16 + l16];
          out[(qrow0 + qsub * 16 + quad * 4 + r) * 256 + dt * 16 + l16] = v;
        }
    }
  }
}

extern "C" void kernel_launch(void* const* d_in, const int* in_sizes, int n_in,
                              void* d_out, int out_size, void* d_ws,
                              size_t ws_size, hipStream_t stream) {
  const float* x = (const float*)d_in[0];
  const float* Wq = (const float*)d_in[1];
  const float* bq = (const float*)d_in[2];
  const float* Wk = (const float*)d_in[3];
  const float* bk = (const float*)d_in[4];
  const float* Wv = (const float*)d_in[5];
  const float* bv = (const float*)d_in[6];
  float* out = (float*)d_out;
  char* ws = (char*)d_ws;

  prep_wt<<<768, 256, 0, stream>>>(Wq, Wk, Wv, (bf16*)(ws + WT_OFF));
  proj_qkv<<<768, 256, 0, stream>>>(x, bq, bk, bv, ws);
  flash_attn<<<256, 512, 0, stream>>>(ws, out);
}